// Round 1
// baseline (350.033 us; speedup 1.0000x reference)
//
#include <hip/hip_runtime.h>

#define N_TOK 8192
#define IN_DIM 1024
#define OUT_DIM 1024
#define NE 8

typedef short short8 __attribute__((ext_vector_type(8)));
typedef float f32x4 __attribute__((ext_vector_type(4)));
typedef ushort ushort4v __attribute__((ext_vector_type(4)));

__device__ __forceinline__ ushort f2bf(float f) {
    union { float f; unsigned u; } v; v.f = f;
    unsigned u = v.u;
    unsigned r = (u + 0x7fffu + ((u >> 16) & 1u)) >> 16;
    return (ushort)r;
}

// ---- x fp32 -> bf16 (same layout, [N][K]) ----
__global__ __launch_bounds__(256) void convert_x(const float* __restrict__ x,
                                                 short* __restrict__ xb) {
    int i = blockIdx.x * 256 + threadIdx.x;      // each handles 8 floats
    const float4* xin = (const float4*)x + (size_t)i * 2;
    float4 a = xin[0], b = xin[1];
    short8 o;
    o[0] = (short)f2bf(a.x); o[1] = (short)f2bf(a.y);
    o[2] = (short)f2bf(a.z); o[3] = (short)f2bf(a.w);
    o[4] = (short)f2bf(b.x); o[5] = (short)f2bf(b.y);
    o[6] = (short)f2bf(b.z); o[7] = (short)f2bf(b.w);
    *((short8*)xb + i) = o;
}

// ---- W [E][K][N] fp32 -> Wt [E][N][K] bf16 (LDS tiled transpose) ----
__global__ __launch_bounds__(256) void transpose_w(const float* __restrict__ W,
                                                   short* __restrict__ wt) {
    int e = blockIdx.z, kt = blockIdx.y, nt = blockIdx.x;
    __shared__ ushort tile[32][33];
    int t = threadIdx.x;
    int r = t >> 3;             // k within tile
    int c4 = (t & 7) * 4;       // n within tile
    const float4 v = *(const float4*)(W + (((size_t)e * 1024 + kt * 32 + r) * 1024) + nt * 32 + c4);
    tile[c4 + 0][r] = f2bf(v.x);
    tile[c4 + 1][r] = f2bf(v.y);
    tile[c4 + 2][r] = f2bf(v.z);
    tile[c4 + 3][r] = f2bf(v.w);
    __syncthreads();
    int n = t >> 3, kq = (t & 7) * 4;
    ushort4v o;
    o[0] = tile[n][kq + 0]; o[1] = tile[n][kq + 1];
    o[2] = tile[n][kq + 2]; o[3] = tile[n][kq + 3];
    *(ushort4v*)(wt + (((size_t)e * 1024 + nt * 32 + n) * 1024) + kt * 32 + kq) = o;
}

// ---- gating: fp32 scores, top-2, softmax, atomic scatter into expert buckets ----
__global__ __launch_bounds__(256) void gating(const float* __restrict__ x,
                                              const float* __restrict__ Wg,
                                              const float* __restrict__ bg,
                                              int* __restrict__ counts,
                                              int* __restrict__ entries,
                                              float* __restrict__ entw) {
    int wid = threadIdx.x >> 6, lane = threadIdx.x & 63;
    int tok = blockIdx.x * 4 + wid;
    const float* xr = x + (size_t)tok * IN_DIM;
    float acc[8];
    #pragma unroll
    for (int e = 0; e < 8; ++e) acc[e] = 0.f;
    for (int j = lane; j < IN_DIM; j += 64) {
        float xv = xr[j];
        float4 wa = *(const float4*)(Wg + (size_t)j * 8);
        float4 wb = *(const float4*)(Wg + (size_t)j * 8 + 4);
        acc[0] += xv * wa.x; acc[1] += xv * wa.y;
        acc[2] += xv * wa.z; acc[3] += xv * wa.w;
        acc[4] += xv * wb.x; acc[5] += xv * wb.y;
        acc[6] += xv * wb.z; acc[7] += xv * wb.w;
    }
    #pragma unroll
    for (int e = 0; e < 8; ++e)
        #pragma unroll
        for (int off = 32; off; off >>= 1)
            acc[e] += __shfl_xor(acc[e], off, 64);
    if (lane == 0) {
        float s[8];
        #pragma unroll
        for (int e = 0; e < 8; ++e) s[e] = acc[e] + bg[e];
        int i0 = 0;
        #pragma unroll
        for (int e = 1; e < 8; ++e) if (s[e] > s[i0]) i0 = e;
        int i1 = (i0 == 0) ? 1 : 0;
        #pragma unroll
        for (int e = 0; e < 8; ++e) if (e != i0 && s[e] > s[i1]) i1 = e;
        float m = s[i0];                      // s[i0] >= s[i1]
        float e0 = __expf(s[i0] - m), e1 = __expf(s[i1] - m);
        float inv = 1.f / (e0 + e1);
        int p0 = atomicAdd(&counts[i0], 1);
        entries[i0 * N_TOK + p0] = tok; entw[i0 * N_TOK + p0] = e0 * inv;
        int p1 = atomicAdd(&counts[i1], 1);
        entries[i1 * N_TOK + p1] = tok; entw[i1 * N_TOK + p1] = e1 * inv;
    }
}

// ---- grouped GEMM: per (expert, row-tile, col-tile); 128x128 tile, BK=32,
//      4 waves (2x2), 16x16x32 bf16 MFMA, gathered A rows, atomic FP32 combine ----
__global__ __launch_bounds__(256) void moe_gemm(const short* __restrict__ xb,
                                                const short* __restrict__ wt,
                                                const float* __restrict__ bias,
                                                const int* __restrict__ counts,
                                                const int* __restrict__ entries,
                                                const float* __restrict__ entw,
                                                float* __restrict__ out) {
    int e = blockIdx.z, rt = blockIdx.y, ct = blockIdx.x;
    int cnt = counts[e];
    if (rt * 128 >= cnt) return;
    int rows = min(128, cnt - rt * 128);

    __shared__ short As[128 * 40];   // [m][k] padded +8 -> ~2-way bank aliasing (free)
    __shared__ short Bs[128 * 40];   // [n][k] padded
    __shared__ int tok_sh[128];
    __shared__ float w_sh[128];

    int t = threadIdx.x;
    int ebase = e * N_TOK + rt * 128;
    if (t < 128) {
        int tk = (t < rows) ? entries[ebase + t] : -1;
        tok_sh[t] = tk;
        w_sh[t] = (t < rows) ? entw[ebase + t] : 0.f;
    }
    __syncthreads();

    int r0 = t >> 2, r1 = r0 + 64;
    int cpos = (t & 3) * 8;
    int tokA0 = tok_sh[r0], tokA1 = tok_sh[r1];
    const short* bA0 = xb + (size_t)(tokA0 < 0 ? 0 : tokA0) * IN_DIM + cpos;
    const short* bA1 = xb + (size_t)(tokA1 < 0 ? 0 : tokA1) * IN_DIM + cpos;
    const short* bB0 = wt + ((size_t)e * OUT_DIM + ct * 128 + r0) * IN_DIM + cpos;
    const short* bB1 = bB0 + (size_t)64 * IN_DIM;
    int wA0 = r0 * 40 + cpos, wA1 = r1 * 40 + cpos;

    int wid = t >> 6, lane = t & 63;
    int wr = wid >> 1, wc = wid & 1;           // 2x2 wave grid, 64x64 per wave
    int frow = lane & 15, fk = (lane >> 4) * 8;
    int aoff[4], boff[4];
    #pragma unroll
    for (int mi = 0; mi < 4; ++mi) aoff[mi] = (wr * 64 + mi * 16 + frow) * 40 + fk;
    #pragma unroll
    for (int ni = 0; ni < 4; ++ni) boff[ni] = (wc * 64 + ni * 16 + frow) * 40 + fk;

    f32x4 acc[4][4];
    #pragma unroll
    for (int mi = 0; mi < 4; ++mi)
        #pragma unroll
        for (int ni = 0; ni < 4; ++ni) acc[mi][ni] = (f32x4)(0.0f);

    for (int kt = 0; kt < 32; ++kt) {
        int k0 = kt * 32;
        short8 va0 = *(const short8*)(bA0 + k0);
        short8 va1 = *(const short8*)(bA1 + k0);
        short8 vb0 = *(const short8*)(bB0 + k0);
        short8 vb1 = *(const short8*)(bB1 + k0);
        __syncthreads();                       // prev iter's reads done
        *(short8*)&As[wA0] = va0;
        *(short8*)&As[wA1] = va1;
        *(short8*)&Bs[wA0] = vb0;              // same [row][k] mapping
        *(short8*)&Bs[wA1] = vb1;
        __syncthreads();
        short8 af[4], bfr[4];
        #pragma unroll
        for (int mi = 0; mi < 4; ++mi) af[mi] = *(const short8*)&As[aoff[mi]];
        #pragma unroll
        for (int ni = 0; ni < 4; ++ni) bfr[ni] = *(const short8*)&Bs[boff[ni]];
        #pragma unroll
        for (int mi = 0; mi < 4; ++mi)
            #pragma unroll
            for (int ni = 0; ni < 4; ++ni)
                acc[mi][ni] = __builtin_amdgcn_mfma_f32_16x16x32_bf16(
                    af[mi], bfr[ni], acc[mi][ni], 0, 0, 0);
    }

    const float* be = bias + (size_t)e * OUT_DIM;
    #pragma unroll
    for (int ni = 0; ni < 4; ++ni) {
        int gcol = ct * 128 + wc * 64 + ni * 16 + (lane & 15);
        float bv = be[gcol];
        #pragma unroll
        for (int mi = 0; mi < 4; ++mi) {
            int rbase = wr * 64 + mi * 16 + (lane >> 4) * 4;
            #pragma unroll
            for (int r = 0; r < 4; ++r) {
                int rloc = rbase + r;
                if (rloc < rows) {
                    int tk = tok_sh[rloc];
                    float w = w_sh[rloc];
                    atomicAdd(out + (size_t)tk * OUT_DIM + gcol,
                              w * (acc[mi][ni][r] + bv));
                }
            }
        }
    }
}

extern "C" void kernel_launch(void* const* d_in, const int* in_sizes, int n_in,
                              void* d_out, int out_size, void* d_ws, size_t ws_size,
                              hipStream_t stream) {
    const float* x  = (const float*)d_in[0];
    const float* W  = (const float*)d_in[1];
    const float* b  = (const float*)d_in[2];
    const float* Wg = (const float*)d_in[3];
    const float* bg = (const float*)d_in[4];
    float* out = (float*)d_out;

    char* ws = (char*)d_ws;
    short* xb      = (short*)(ws);                       // 16 MiB
    short* wt      = (short*)(ws + 16777216);            // 16 MiB
    int* entries   = (int*)(ws + 33554432);              // 256 KiB
    float* entw    = (float*)(ws + 33816576);            // 256 KiB
    int* counts    = (int*)(ws + 34078720);              // 32 B

    hipMemsetAsync(out, 0, (size_t)N_TOK * OUT_DIM * sizeof(float), stream);
    hipMemsetAsync(counts, 0, NE * sizeof(int), stream);

    convert_x<<<4096, 256, 0, stream>>>(x, xb);
    transpose_w<<<dim3(32, 32, 8), 256, 0, stream>>>(W, wt);
    gating<<<2048, 256, 0, stream>>>(x, Wg, bg, counts, entries, entw);
    moe_gemm<<<dim3(8, 64, 8), 256, 0, stream>>>(xb, wt, b, counts, entries, entw, out);
}

// Round 2
// 192.200 us; speedup vs baseline: 1.8212x; 1.8212x over previous
//
#include <hip/hip_runtime.h>

#define N_TOK 8192
#define IN_DIM 1024
#define OUT_DIM 1024
#define NE 8

typedef short short8 __attribute__((ext_vector_type(8)));
typedef float f32x4 __attribute__((ext_vector_type(4)));
typedef ushort ushort4v __attribute__((ext_vector_type(4)));

__device__ __forceinline__ ushort f2bf(float f) {
    union { float f; unsigned u; } v; v.f = f;
    unsigned u = v.u;
    unsigned r = (u + 0x7fffu + ((u >> 16) & 1u)) >> 16;
    return (ushort)r;
}

__device__ __forceinline__ void gl_lds16(const short* g, short* l) {
    __builtin_amdgcn_global_load_lds(
        (const __attribute__((address_space(1))) unsigned int*)g,
        (__attribute__((address_space(3))) unsigned int*)l, 16, 0, 0);
}

// ---- Phase A: gating scores (fp32) + top-2 + x->bf16 convert, NO atomics ----
__global__ __launch_bounds__(256) void gate_convert(const float* __restrict__ x,
                                                    const float* __restrict__ Wg,
                                                    const float* __restrict__ bg,
                                                    short* __restrict__ xb,
                                                    unsigned* __restrict__ choice,
                                                    float2* __restrict__ wts) {
    int wid = threadIdx.x >> 6, lane = threadIdx.x & 63;
    int tok = blockIdx.x * 4 + wid;
    const float* xr = x + (size_t)tok * IN_DIM;
    short* xbr = xb + (size_t)tok * IN_DIM;
    float acc[8];
    #pragma unroll
    for (int e = 0; e < 8; ++e) acc[e] = 0.f;
    #pragma unroll
    for (int it = 0; it < 4; ++it) {
        int j = it * 256 + lane * 4;
        float4 v = *(const float4*)(xr + j);
        ushort4v o;
        o[0] = f2bf(v.x); o[1] = f2bf(v.y); o[2] = f2bf(v.z); o[3] = f2bf(v.w);
        *(ushort4v*)(xbr + j) = o;
        #pragma unroll
        for (int r = 0; r < 4; ++r) {
            float xv = (r == 0) ? v.x : (r == 1) ? v.y : (r == 2) ? v.z : v.w;
            float4 wa = *(const float4*)(Wg + (size_t)(j + r) * 8);
            float4 wb = *(const float4*)(Wg + (size_t)(j + r) * 8 + 4);
            acc[0] += xv * wa.x; acc[1] += xv * wa.y;
            acc[2] += xv * wa.z; acc[3] += xv * wa.w;
            acc[4] += xv * wb.x; acc[5] += xv * wb.y;
            acc[6] += xv * wb.z; acc[7] += xv * wb.w;
        }
    }
    #pragma unroll
    for (int e = 0; e < 8; ++e)
        #pragma unroll
        for (int off = 32; off; off >>= 1)
            acc[e] += __shfl_xor(acc[e], off, 64);
    if (lane == 0) {
        float s[8];
        #pragma unroll
        for (int e = 0; e < 8; ++e) s[e] = acc[e] + bg[e];
        int i0 = 0;
        #pragma unroll
        for (int e = 1; e < 8; ++e) if (s[e] > s[i0]) i0 = e;
        int i1 = (i0 == 0) ? 1 : 0;
        #pragma unroll
        for (int e = 0; e < 8; ++e) if (e != i0 && s[e] > s[i1]) i1 = e;
        float e0 = 1.f, e1 = __expf(s[i1] - s[i0]);
        float inv = 1.f / (e0 + e1);
        choice[tok] = (unsigned)i0 | ((unsigned)i1 << 8);
        wts[tok] = make_float2(e0 * inv, e1 * inv);
    }
}

// ---- Phase B: deterministic bucketing, one block per expert, ballot prefix-sum ----
__global__ __launch_bounds__(1024) void bucket(const unsigned* __restrict__ choice,
                                               const float2* __restrict__ wts,
                                               int* __restrict__ counts,
                                               int* __restrict__ entries,
                                               float* __restrict__ entw) {
    int e = blockIdx.x;
    int t = threadIdx.x;
    int wid = t >> 6, lane = t & 63;
    __shared__ int wsum[16];
    int base = 0;
    for (int chunk = 0; chunk < 8; ++chunk) {
        int tok = chunk * 1024 + t;
        unsigned c = choice[tok];
        float2 w = wts[tok];
        int which = ((int)(c & 255u) == e) ? 0 : (((int)((c >> 8) & 255u) == e) ? 1 : -1);
        unsigned long long m = __ballot(which >= 0);
        if (lane == 0) wsum[wid] = __popcll(m);
        __syncthreads();
        int woff = base;
        #pragma unroll
        for (int i = 0; i < 16; ++i) if (i < wid) woff += wsum[i];
        int tot = 0;
        #pragma unroll
        for (int i = 0; i < 16; ++i) tot += wsum[i];
        if (which >= 0) {
            int rank = __popcll(m & ((1ull << lane) - 1ull));
            int pos = e * N_TOK + woff + rank;
            entries[pos] = tok;
            entw[pos] = (which == 0) ? w.x : w.y;
        }
        base += tot;
        __syncthreads();
    }
    if (t == 0) counts[e] = base;
}

// ---- W [E][K][N] fp32 -> Wt [E][N][K] bf16 (LDS tiled transpose) ----
__global__ __launch_bounds__(256) void transpose_w(const float* __restrict__ W,
                                                   short* __restrict__ wt) {
    int e = blockIdx.z, kt = blockIdx.y, nt = blockIdx.x;
    __shared__ ushort tile[32][33];
    int t = threadIdx.x;
    int r = t >> 3;
    int c4 = (t & 7) * 4;
    const float4 v = *(const float4*)(W + (((size_t)e * 1024 + kt * 32 + r) * 1024) + nt * 32 + c4);
    tile[c4 + 0][r] = f2bf(v.x);
    tile[c4 + 1][r] = f2bf(v.y);
    tile[c4 + 2][r] = f2bf(v.z);
    tile[c4 + 3][r] = f2bf(v.w);
    __syncthreads();
    int n = t >> 3, kq = (t & 7) * 4;
    ushort4v o;
    o[0] = tile[n][kq + 0]; o[1] = tile[n][kq + 1];
    o[2] = tile[n][kq + 2]; o[3] = tile[n][kq + 3];
    *(ushort4v*)(wt + (((size_t)e * 1024 + nt * 32 + n) * 1024) + kt * 32 + kq) = o;
}

// ---- grouped GEMM: 128x128 tile, BK=64, global_load_lds staging,
//      XOR-swizzled LDS (16B chunk ^= row&7), 2-barrier K-loop, atomic combine ----
__global__ __launch_bounds__(256) void moe_gemm(const short* __restrict__ xb,
                                                const short* __restrict__ wt,
                                                const float* __restrict__ bias,
                                                const int* __restrict__ counts,
                                                const int* __restrict__ entries,
                                                const float* __restrict__ entw,
                                                float* __restrict__ out) {
    int e = blockIdx.z, rt = blockIdx.y, ct = blockIdx.x;
    int cnt = counts[e];
    if (rt * 128 >= cnt) return;
    int rows = min(128, cnt - rt * 128);

    __shared__ short As[128 * 64];
    __shared__ short Bs[128 * 64];
    __shared__ int tok_sh[128];
    __shared__ float w_sh[128];

    int t = threadIdx.x;
    int wid = t >> 6, lane = t & 63;
    int ebase = e * N_TOK + rt * 128;
    if (t < 128) {
        tok_sh[t] = (t < rows) ? entries[ebase + t] : 0;
        w_sh[t] = (t < rows) ? entw[ebase + t] : 0.f;
    }
    __syncthreads();

    // staging: wave covers 8 rows per instr (128B/row); src k-chunk pre-swizzled
    const short* asrc[4];
    const short* bsrc[4];
    short* alds[4];
    short* blds[4];
    int sl = lane & 7;
    #pragma unroll
    for (int i = 0; i < 4; ++i) {
        int r = wid * 32 + i * 8 + (lane >> 3);
        int koff = ((sl ^ (r & 7)) * 8);
        asrc[i] = xb + (size_t)tok_sh[r] * IN_DIM + koff;
        bsrc[i] = wt + ((size_t)e * OUT_DIM + ct * 128 + r) * IN_DIM + koff;
        alds[i] = As + (wid * 4 + i) * 512 + lane * 8;
        blds[i] = Bs + (wid * 4 + i) * 512 + lane * 8;
    }

    int wr = wid >> 1, wc = wid & 1;   // 2x2 wave grid, 64x64 per wave
    int frow = lane & 15, fslot = lane >> 4;
    int aoff[2][4], boff[2][4];        // short-unit LDS offsets, swizzled
    #pragma unroll
    for (int i = 0; i < 4; ++i) {
        int ra = wr * 64 + i * 16 + frow;
        int rb = wc * 64 + i * 16 + frow;
        #pragma unroll
        for (int kk = 0; kk < 2; ++kk) {
            aoff[kk][i] = ra * 64 + (((kk * 4 + fslot) ^ (ra & 7)) * 8);
            boff[kk][i] = rb * 64 + (((kk * 4 + fslot) ^ (rb & 7)) * 8);
        }
    }

    f32x4 acc[4][4];
    #pragma unroll
    for (int mi = 0; mi < 4; ++mi)
        #pragma unroll
        for (int ni = 0; ni < 4; ++ni) acc[mi][ni] = (f32x4)(0.0f);

    for (int kt = 0; kt < IN_DIM / 64; ++kt) {
        int k0 = kt * 64;
        __syncthreads();               // prev iter's LDS reads complete
        #pragma unroll
        for (int i = 0; i < 4; ++i) {
            gl_lds16(asrc[i] + k0, alds[i]);
            gl_lds16(bsrc[i] + k0, blds[i]);
        }
        __syncthreads();               // staged data visible (vmcnt(0) at barrier)
        #pragma unroll
        for (int kk = 0; kk < 2; ++kk) {
            short8 af[4], bf2[4];
            #pragma unroll
            for (int mi = 0; mi < 4; ++mi) af[mi] = *(const short8*)(As + aoff[kk][mi]);
            #pragma unroll
            for (int ni = 0; ni < 4; ++ni) bf2[ni] = *(const short8*)(Bs + boff[kk][ni]);
            #pragma unroll
            for (int mi = 0; mi < 4; ++mi)
                #pragma unroll
                for (int ni = 0; ni < 4; ++ni)
                    acc[mi][ni] = __builtin_amdgcn_mfma_f32_16x16x32_bf16(
                        af[mi], bf2[ni], acc[mi][ni], 0, 0, 0);
        }
    }

    const float* be = bias + (size_t)e * OUT_DIM;
    #pragma unroll
    for (int ni = 0; ni < 4; ++ni) {
        int gcol = ct * 128 + wc * 64 + ni * 16 + (lane & 15);
        float bv = be[gcol];
        #pragma unroll
        for (int mi = 0; mi < 4; ++mi) {
            int rbase = wr * 64 + mi * 16 + (lane >> 4) * 4;
            #pragma unroll
            for (int r = 0; r < 4; ++r) {
                int rloc = rbase + r;
                if (rloc < rows) {
                    int tk = tok_sh[rloc];
                    float w = w_sh[rloc];
                    atomicAdd(out + (size_t)tk * OUT_DIM + gcol,
                              w * (acc[mi][ni][r] + bv));
                }
            }
        }
    }
}

extern "C" void kernel_launch(void* const* d_in, const int* in_sizes, int n_in,
                              void* d_out, int out_size, void* d_ws, size_t ws_size,
                              hipStream_t stream) {
    const float* x  = (const float*)d_in[0];
    const float* W  = (const float*)d_in[1];
    const float* b  = (const float*)d_in[2];
    const float* Wg = (const float*)d_in[3];
    const float* bg = (const float*)d_in[4];
    float* out = (float*)d_out;

    char* ws = (char*)d_ws;
    short* xb       = (short*)(ws);                      // 16 MiB
    short* wt       = (short*)(ws + 16777216);           // 16 MiB
    // choice/wts overlay the tail of wt: written by gate_convert, consumed by
    // bucket, then overwritten by transpose_w (launched after bucket).
    unsigned* choice = (unsigned*)(ws + 33456128);       // 32 KiB
    float2* wts      = (float2*)(ws + 33488896);         // 64 KiB
    int* entries    = (int*)(ws + 33554432);             // 256 KiB
    float* entw     = (float*)(ws + 33816576);           // 256 KiB
    int* counts     = (int*)(ws + 34078720);             // 32 B

    hipMemsetAsync(out, 0, (size_t)N_TOK * OUT_DIM * sizeof(float), stream);

    gate_convert<<<2048, 256, 0, stream>>>(x, Wg, bg, xb, choice, wts);
    bucket<<<8, 1024, 0, stream>>>(choice, wts, counts, entries, entw);
    transpose_w<<<dim3(32, 32, 8), 256, 0, stream>>>(W, wt);
    moe_gemm<<<dim3(8, 64, 8), 256, 0, stream>>>(xb, wt, b, counts, entries, entw, out);
}

// Round 3
// 149.618 us; speedup vs baseline: 2.3395x; 1.2846x over previous
//
#include <hip/hip_runtime.h>

#define N_TOK 8192
#define IN_DIM 1024
#define OUT_DIM 1024
#define NE 8
#define BUFE (128 * 64)

typedef short short8 __attribute__((ext_vector_type(8)));
typedef float f32x4 __attribute__((ext_vector_type(4)));
typedef ushort ushort4v __attribute__((ext_vector_type(4)));

__device__ __forceinline__ ushort f2bf(float f) {
    union { float f; unsigned u; } v; v.f = f;
    unsigned u = v.u;
    unsigned r = (u + 0x7fffu + ((u >> 16) & 1u)) >> 16;
    return (ushort)r;
}

__device__ __forceinline__ float bf2f(short s) {
    union { unsigned u; float f; } v;
    v.u = ((unsigned)(unsigned short)s) << 16;
    return v.f;
}

__device__ __forceinline__ void gl_lds16(const short* g, short* l) {
    __builtin_amdgcn_global_load_lds(
        (const __attribute__((address_space(1))) unsigned int*)g,
        (__attribute__((address_space(3))) unsigned int*)l, 16, 0, 0);
}

// ---- Phase A: gating scores (fp32) + top-2 + x->bf16 convert, NO atomics ----
__global__ __launch_bounds__(256) void gate_convert(const float* __restrict__ x,
                                                    const float* __restrict__ Wg,
                                                    const float* __restrict__ bg,
                                                    short* __restrict__ xb,
                                                    unsigned* __restrict__ choice,
                                                    float2* __restrict__ wts) {
    int wid = threadIdx.x >> 6, lane = threadIdx.x & 63;
    int tok = blockIdx.x * 4 + wid;
    const float* xr = x + (size_t)tok * IN_DIM;
    short* xbr = xb + (size_t)tok * IN_DIM;
    float acc[8];
    #pragma unroll
    for (int e = 0; e < 8; ++e) acc[e] = 0.f;
    #pragma unroll
    for (int it = 0; it < 4; ++it) {
        int j = it * 256 + lane * 4;
        float4 v = *(const float4*)(xr + j);
        ushort4v o;
        o[0] = f2bf(v.x); o[1] = f2bf(v.y); o[2] = f2bf(v.z); o[3] = f2bf(v.w);
        *(ushort4v*)(xbr + j) = o;
        #pragma unroll
        for (int r = 0; r < 4; ++r) {
            float xv = (r == 0) ? v.x : (r == 1) ? v.y : (r == 2) ? v.z : v.w;
            float4 wa = *(const float4*)(Wg + (size_t)(j + r) * 8);
            float4 wb = *(const float4*)(Wg + (size_t)(j + r) * 8 + 4);
            acc[0] += xv * wa.x; acc[1] += xv * wa.y;
            acc[2] += xv * wa.z; acc[3] += xv * wa.w;
            acc[4] += xv * wb.x; acc[5] += xv * wb.y;
            acc[6] += xv * wb.z; acc[7] += xv * wb.w;
        }
    }
    #pragma unroll
    for (int e = 0; e < 8; ++e)
        #pragma unroll
        for (int off = 32; off; off >>= 1)
            acc[e] += __shfl_xor(acc[e], off, 64);
    if (lane == 0) {
        float s[8];
        #pragma unroll
        for (int e = 0; e < 8; ++e) s[e] = acc[e] + bg[e];
        int i0 = 0;
        #pragma unroll
        for (int e = 1; e < 8; ++e) if (s[e] > s[i0]) i0 = e;
        int i1 = (i0 == 0) ? 1 : 0;
        #pragma unroll
        for (int e = 0; e < 8; ++e) if (e != i0 && s[e] > s[i1]) i1 = e;
        float e0 = 1.f, e1 = __expf(s[i1] - s[i0]);
        float inv = 1.f / (e0 + e1);
        choice[tok] = (unsigned)i0 | ((unsigned)i1 << 8);
        wts[tok] = make_float2(e0 * inv, e1 * inv);
    }
}

// ---- Phase B: deterministic bucketing + per-token inverse index, no atomics ----
__global__ __launch_bounds__(1024) void bucket(const unsigned* __restrict__ choice,
                                               const float2* __restrict__ wts,
                                               int* __restrict__ counts,
                                               int* __restrict__ entries,
                                               float* __restrict__ entw,
                                               int* __restrict__ inv0,
                                               int* __restrict__ inv1) {
    int e = blockIdx.x;
    int t = threadIdx.x;
    int wid = t >> 6, lane = t & 63;
    __shared__ int wsum[16];
    int base = 0;
    for (int chunk = 0; chunk < 8; ++chunk) {
        int tok = chunk * 1024 + t;
        unsigned c = choice[tok];
        float2 w = wts[tok];
        int which = ((int)(c & 255u) == e) ? 0 : (((int)((c >> 8) & 255u) == e) ? 1 : -1);
        unsigned long long m = __ballot(which >= 0);
        if (lane == 0) wsum[wid] = __popcll(m);
        __syncthreads();
        int woff = base;
        #pragma unroll
        for (int i = 0; i < 16; ++i) if (i < wid) woff += wsum[i];
        int tot = 0;
        #pragma unroll
        for (int i = 0; i < 16; ++i) tot += wsum[i];
        if (which >= 0) {
            int rank = __popcll(m & ((1ull << lane) - 1ull));
            int idx = woff + rank;                 // position within expert e's list
            entries[e * N_TOK + idx] = tok;
            entw[e * N_TOK + idx] = (which == 0) ? w.x : w.y;
            if (which == 0) inv0[tok] = idx; else inv1[tok] = idx;
        }
        base += tot;
        __syncthreads();
    }
    if (t == 0) counts[e] = base;
}

// ---- W [E][K][N] fp32 -> Wt [E][N][K] bf16 (LDS tiled transpose) ----
__global__ __launch_bounds__(256) void transpose_w(const float* __restrict__ W,
                                                   short* __restrict__ wt) {
    int e = blockIdx.z, kt = blockIdx.y, nt = blockIdx.x;
    __shared__ ushort tile[32][33];
    int t = threadIdx.x;
    int r = t >> 3;
    int c4 = (t & 7) * 4;
    const float4 v = *(const float4*)(W + (((size_t)e * 1024 + kt * 32 + r) * 1024) + nt * 32 + c4);
    tile[c4 + 0][r] = f2bf(v.x);
    tile[c4 + 1][r] = f2bf(v.y);
    tile[c4 + 2][r] = f2bf(v.z);
    tile[c4 + 3][r] = f2bf(v.w);
    __syncthreads();
    int n = t >> 3, kq = (t & 7) * 4;
    ushort4v o;
    o[0] = tile[n][kq + 0]; o[1] = tile[n][kq + 1];
    o[2] = tile[n][kq + 2]; o[3] = tile[n][kq + 3];
    *(ushort4v*)(wt + (((size_t)e * 1024 + nt * 32 + n) * 1024) + kt * 32 + kq) = o;
}

// ---- grouped GEMM: 128x128 tile, BK=64, DOUBLE-BUFFERED global_load_lds
//      pipeline (stage-early, one barrier per K-tile), XOR-swizzled LDS,
//      epilogue: plain bf16 stores to compact ys (or atomic fallback) ----
__global__ __launch_bounds__(256) void moe_gemm(const short* __restrict__ xb,
                                                const short* __restrict__ wt,
                                                const float* __restrict__ bias,
                                                const int* __restrict__ counts,
                                                const int* __restrict__ entries,
                                                const float* __restrict__ entw,
                                                short* __restrict__ ys,
                                                float* __restrict__ out,
                                                int use_ys) {
    // XCD-aware bijective swizzle: 4096 blocks, XCD k gets ids k*512..k*512+511
    // = exactly expert k (its 2 MB B-panel fits one XCD's L2).
    int lin = blockIdx.x;
    int id = (lin & 7) * 512 + (lin >> 3);
    int ct = id & 7, rt = (id >> 3) & 63, e = id >> 9;
    int cnt = counts[e];
    if (rt * 128 >= cnt) return;
    int rows = min(128, cnt - rt * 128);
    int base_e = 0;
    #pragma unroll
    for (int i = 0; i < 8; ++i) base_e += (i < e) ? counts[i] : 0;

    __shared__ short As[2 * BUFE];
    __shared__ short Bs[2 * BUFE];
    __shared__ int tok_sh[128];
    __shared__ float w_sh[128];

    int t = threadIdx.x;
    int wid = t >> 6, lane = t & 63;
    int ebase = e * N_TOK + rt * 128;
    if (t < 128) {
        tok_sh[t] = (t < rows) ? entries[ebase + t] : 0;
        w_sh[t] = (t < rows) ? entw[ebase + t] : 0.f;
    }
    __syncthreads();

    // staging addresses: wave covers 8 rows/instr; src k-chunk pre-swizzled
    const short* asrc[4];
    const short* bsrc[4];
    int ldso[4];
    int sl = lane & 7;
    #pragma unroll
    for (int i = 0; i < 4; ++i) {
        int r = wid * 32 + i * 8 + (lane >> 3);
        int koff = (sl ^ (r & 7)) * 8;
        asrc[i] = xb + (size_t)tok_sh[r] * IN_DIM + koff;
        bsrc[i] = wt + ((size_t)e * OUT_DIM + ct * 128 + r) * IN_DIM + koff;
        ldso[i] = (wid * 4 + i) * 512 + lane * 8;
    }

    int wr = wid >> 1, wc = wid & 1;   // 2x2 wave grid, 64x64 per wave
    int frow = lane & 15, fslot = lane >> 4;
    int aoff[2][4], boff[2][4];        // short-unit LDS offsets, swizzled
    #pragma unroll
    for (int i = 0; i < 4; ++i) {
        int ra = wr * 64 + i * 16 + frow;
        int rb = wc * 64 + i * 16 + frow;
        #pragma unroll
        for (int kk = 0; kk < 2; ++kk) {
            aoff[kk][i] = ra * 64 + (((kk * 4 + fslot) ^ (ra & 7)) * 8);
            boff[kk][i] = rb * 64 + (((kk * 4 + fslot) ^ (rb & 7)) * 8);
        }
    }

    f32x4 acc[4][4];
    #pragma unroll
    for (int mi = 0; mi < 4; ++mi)
        #pragma unroll
        for (int ni = 0; ni < 4; ++ni) acc[mi][ni] = (f32x4)(0.0f);

    auto stage = [&](int kt, short* ab, short* bb) {
        int k0 = kt * 64;
        #pragma unroll
        for (int i = 0; i < 4; ++i) {
            gl_lds16(asrc[i] + k0, ab + ldso[i]);
            gl_lds16(bsrc[i] + k0, bb + ldso[i]);
        }
    };
    auto compute = [&](const short* ab, const short* bb) {
        #pragma unroll
        for (int kk = 0; kk < 2; ++kk) {
            short8 af[4], bf8[4];
            #pragma unroll
            for (int mi = 0; mi < 4; ++mi) af[mi] = *(const short8*)(ab + aoff[kk][mi]);
            #pragma unroll
            for (int ni = 0; ni < 4; ++ni) bf8[ni] = *(const short8*)(bb + boff[kk][ni]);
            #pragma unroll
            for (int mi = 0; mi < 4; ++mi)
                #pragma unroll
                for (int ni = 0; ni < 4; ++ni)
                    acc[mi][ni] = __builtin_amdgcn_mfma_f32_16x16x32_bf16(
                        af[mi], bf8[ni], acc[mi][ni], 0, 0, 0);
        }
    };

    // prologue: stage tile 0 into buffer 0
    stage(0, As, Bs);
    __syncthreads();

    // 2x-unrolled double-buffer loop: stage next tile EARLY, compute current,
    // single barrier per K-tile (drains vmcnt -> next buffer ready).
    for (int kt2 = 0; kt2 < 8; ++kt2) {
        stage(kt2 * 2 + 1, As + BUFE, Bs + BUFE);
        compute(As, Bs);
        __syncthreads();
        if (kt2 < 7) stage(kt2 * 2 + 2, As, Bs);
        compute(As + BUFE, Bs + BUFE);
        __syncthreads();
    }

    const float* be = bias + (size_t)e * OUT_DIM;
    if (use_ys) {
        #pragma unroll
        for (int ni = 0; ni < 4; ++ni) {
            int gcol = ct * 128 + wc * 64 + ni * 16 + frow;
            float bv = be[gcol];
            #pragma unroll
            for (int mi = 0; mi < 4; ++mi) {
                int rbase = wr * 64 + mi * 16 + fslot * 4;
                #pragma unroll
                for (int r = 0; r < 4; ++r) {
                    int rloc = rbase + r;
                    if (rloc < rows) {
                        int grow = base_e + rt * 128 + rloc;
                        ys[(size_t)grow * OUT_DIM + gcol] = (short)f2bf(acc[mi][ni][r] + bv);
                    }
                }
            }
        }
    } else {
        #pragma unroll
        for (int ni = 0; ni < 4; ++ni) {
            int gcol = ct * 128 + wc * 64 + ni * 16 + frow;
            float bv = be[gcol];
            #pragma unroll
            for (int mi = 0; mi < 4; ++mi) {
                int rbase = wr * 64 + mi * 16 + fslot * 4;
                #pragma unroll
                for (int r = 0; r < 4; ++r) {
                    int rloc = rbase + r;
                    if (rloc < rows) {
                        int tk = tok_sh[rloc];
                        float w = w_sh[rloc];
                        atomicAdd(out + (size_t)tk * OUT_DIM + gcol,
                                  w * (acc[mi][ni][r] + bv));
                    }
                }
            }
        }
    }
}

// ---- combine: out[tok] = w0*ys[pos0] + w1*ys[pos1] ----
__global__ __launch_bounds__(256) void combine(const short* __restrict__ ys,
                                               const unsigned* __restrict__ choice,
                                               const float2* __restrict__ wts,
                                               const int* __restrict__ inv0,
                                               const int* __restrict__ inv1,
                                               const int* __restrict__ counts,
                                               float* __restrict__ out) {
    __shared__ int bases[8];
    if (threadIdx.x < 8) {
        int s = 0;
        #pragma unroll
        for (int i = 0; i < 8; ++i) s += (i < (int)threadIdx.x) ? counts[i] : 0;
        bases[threadIdx.x] = s;
    }
    __syncthreads();
    int tok = blockIdx.x * 2 + (threadIdx.x >> 7);
    int c8 = (threadIdx.x & 127) * 8;
    unsigned ch = choice[tok];
    float2 w = wts[tok];
    int p0 = bases[ch & 255u] + inv0[tok];
    int p1 = bases[(ch >> 8) & 255u] + inv1[tok];
    short8 a = *(const short8*)(ys + (size_t)p0 * OUT_DIM + c8);
    short8 b = *(const short8*)(ys + (size_t)p1 * OUT_DIM + c8);
    float* op = out + (size_t)tok * OUT_DIM + c8;
    float4 o0, o1;
    o0.x = w.x * bf2f(a[0]) + w.y * bf2f(b[0]);
    o0.y = w.x * bf2f(a[1]) + w.y * bf2f(b[1]);
    o0.z = w.x * bf2f(a[2]) + w.y * bf2f(b[2]);
    o0.w = w.x * bf2f(a[3]) + w.y * bf2f(b[3]);
    o1.x = w.x * bf2f(a[4]) + w.y * bf2f(b[4]);
    o1.y = w.x * bf2f(a[5]) + w.y * bf2f(b[5]);
    o1.z = w.x * bf2f(a[6]) + w.y * bf2f(b[6]);
    o1.w = w.x * bf2f(a[7]) + w.y * bf2f(b[7]);
    *(float4*)op = o0;
    *(float4*)(op + 4) = o1;
}

extern "C" void kernel_launch(void* const* d_in, const int* in_sizes, int n_in,
                              void* d_out, int out_size, void* d_ws, size_t ws_size,
                              hipStream_t stream) {
    const float* x  = (const float*)d_in[0];
    const float* W  = (const float*)d_in[1];
    const float* b  = (const float*)d_in[2];
    const float* Wg = (const float*)d_in[3];
    const float* bg = (const float*)d_in[4];
    float* out = (float*)d_out;

    char* ws = (char*)d_ws;
    short* xb        = (short*)(ws);                     // 16 MiB
    short* wt        = (short*)(ws + 16777216);          // 16 MiB
    unsigned* choice = (unsigned*)(ws + 33554432);       // 32 KiB
    float2* wts      = (float2*)(ws + 33587200);         // 64 KiB
    int* inv0        = (int*)(ws + 33652736);            // 32 KiB
    int* inv1        = (int*)(ws + 33685504);            // 32 KiB
    int* entries     = (int*)(ws + 33718272);            // 256 KiB
    float* entw      = (float*)(ws + 33980416);          // 256 KiB
    int* counts      = (int*)(ws + 34242560);            // 64 B
    short* ys        = (short*)(ws + 34242624);          // 32 MiB (ys mode only)

    const size_t need_ys = 34242624ull + (size_t)2 * N_TOK * OUT_DIM * 2;
    int use_ys = (ws_size >= need_ys) ? 1 : 0;

    if (!use_ys)
        hipMemsetAsync(out, 0, (size_t)N_TOK * OUT_DIM * sizeof(float), stream);

    gate_convert<<<2048, 256, 0, stream>>>(x, Wg, bg, xb, choice, wts);
    bucket<<<8, 1024, 0, stream>>>(choice, wts, counts, entries, entw, inv0, inv1);
    transpose_w<<<dim3(32, 32, 8), 256, 0, stream>>>(W, wt);
    moe_gemm<<<4096, 256, 0, stream>>>(xb, wt, b, counts, entries, entw, ys, out, use_ys);
    if (use_ys)
        combine<<<4096, 256, 0, stream>>>(ys, choice, wts, inv0, inv1, counts, out);
}